// Round 5
// baseline (2557.590 us; speedup 1.0000x reference)
//
#include <hip/hip_runtime.h>
#include <cmath>

typedef unsigned int u32;

// Problem constants
#define NBATCH 128
#define NT 64
#define ND 768
#define NU 256
#define NV 48

// Uw residency split (k4-rows of 4 k-values each; 64 rows total):
//   rows [0, NR4V)            -> VGPRs (UR, 4*NR4V regs/thread)
//   rows [NR4V, NR4V+NRL)     -> LDS   (UL, 16KB/row)
//   rows [NR4V+NRL, 64)       -> streamed from L2 each step
#define NR4V 20
#define NRL  5
#define NRES (NR4V + NRL)

// ws layout (bytes)
#define WS_INPW 0                          // inpW[128*64][1024] f32 = 33,554,432
#define WS_EMBW 33554432                   // embW[48][1024] f32   = 196,608
#define WS_UWS  (WS_EMBW + 196608)         // Uws [64][1024] float4 = 1,048,576
#define WS_WOT  (WS_UWS + 1048576)         // WotG[48][256] f32    = 49,152

__device__ __forceinline__ float sigf(float x) { return 1.0f / (1.0f + expf(-x)); }

// ---------------------------------------------------------------------------
// inpW[(b*64+t)][c] = inputs[b][t][:] @ W[256:1024][c]   (M=8192,N=1024,K=768)
// ---------------------------------------------------------------------------
__global__ __launch_bounds__(256) void prep_inpw(
    const float* __restrict__ inputs, const float* __restrict__ W,
    float* __restrict__ inpW) {
  __shared__ float Af[64][36];
  __shared__ float Bf[32][68];
  const int mt = blockIdx.x >> 4, nt = blockIdx.x & 15;
  const int m0 = mt * 64, n0 = nt * 64;
  const int tid = threadIdx.x;
  const int ty = tid >> 4, tx = tid & 15;
  const float4* in4 = (const float4*)inputs;
  const float4* W4 = (const float4*)W;
  float acc[4][4] = {};
  for (int kt = 0; kt < 24; ++kt) {
    __syncthreads();
    {
      int idx = tid;
#pragma unroll
      for (int r = 0; r < 2; ++r, idx += 256) {
        const int row = idx >> 3, k4 = idx & 7;
        const float4 a = in4[(size_t)(m0 + row) * 192 + kt * 8 + k4];
        *(float4*)&Af[row][4 * k4] = a;
      }
    }
    {
      int idx = tid;
#pragma unroll
      for (int r = 0; r < 2; ++r, idx += 256) {
        const int kk = idx >> 4, c4 = idx & 15;
        const float4 bv = W4[(size_t)(256 + kt * 32 + kk) * 256 + (n0 >> 2) + c4];
        *(float4*)&Bf[kk][4 * c4] = bv;
      }
    }
    __syncthreads();
#pragma unroll 4
    for (int kk = 0; kk < 32; ++kk) {
      float av[4], bv[4];
#pragma unroll
      for (int j = 0; j < 4; ++j) av[j] = Af[ty * 4 + j][kk];
#pragma unroll
      for (int j = 0; j < 4; ++j) bv[j] = Bf[kk][tx * 4 + j];
#pragma unroll
      for (int i = 0; i < 4; ++i)
#pragma unroll
        for (int j = 0; j < 4; ++j) acc[i][j] = fmaf(av[i], bv[j], acc[i][j]);
    }
  }
#pragma unroll
  for (int i = 0; i < 4; ++i) {
    const float4 o = make_float4(acc[i][0], acc[i][1], acc[i][2], acc[i][3]);
    ((float4*)inpW)[(((size_t)(m0 + ty * 4 + i)) * 1024 + n0 + tx * 4) >> 2] = o;
  }
}

// ---------------------------------------------------------------------------
// embW[v][c] = bias[c] + embed[v][:] @ W[0:256][c]
// ---------------------------------------------------------------------------
__global__ __launch_bounds__(256) void prep_embw(
    const float* __restrict__ embed, const float* __restrict__ W,
    const float* __restrict__ bias, float* __restrict__ embW) {
  const int v = blockIdx.x, tid = threadIdx.x;
  const float4* W4 = (const float4*)W;
  float4 acc = ((const float4*)bias)[tid];
  for (int e = 0; e < 256; ++e) {
    const float s = embed[v * 256 + e];
    const float4 w = W4[(size_t)e * 256 + tid];
    acc.x = fmaf(s, w.x, acc.x); acc.y = fmaf(s, w.y, acc.y);
    acc.z = fmaf(s, w.z, acc.z); acc.w = fmaf(s, w.w, acc.w);
  }
  ((float4*)embW)[v * 256 + tid] = acc;
}

// ---------------------------------------------------------------------------
// Uws element (k4, c) = float4{ Uw[4k4+0][c], .., Uw[4k4+3][c] }
// ---------------------------------------------------------------------------
__global__ __launch_bounds__(256) void prep_uws(
    const float* __restrict__ Uw, float* __restrict__ Uws) {
  const int k4 = blockIdx.x, tid = threadIdx.x;
#pragma unroll
  for (int j = 0; j < 4; ++j) {
    const int cc = tid + 256 * j;
    float4 o;
    o.x = Uw[(size_t)(4 * k4 + 0) * 1024 + cc];
    o.y = Uw[(size_t)(4 * k4 + 1) * 1024 + cc];
    o.z = Uw[(size_t)(4 * k4 + 2) * 1024 + cc];
    o.w = Uw[(size_t)(4 * k4 + 3) * 1024 + cc];
    ((float4*)Uws)[(size_t)k4 * 1024 + cc] = o;
  }
}

// Wot[v][u] = Wo[u][v]
__global__ void prep_wot(const float* __restrict__ Wo, float* __restrict__ WotG) {
  const int tid = threadIdx.x;
  for (int v = 0; v < NV; ++v) WotG[v * 256 + tid] = Wo[tid * NV + v];
}

// ---------------------------------------------------------------------------
// Persistent per-batch decoder: 64 blocks x 1024 threads, 2 batches/block,
// no cross-block communication. launch_bounds(1024,4): 4 waves/EU min ->
// 128-VGPR cap -> 1 block/CU -> UR stays in registers (R4 spilled at 64).
// Thread c owns gate column c: Uw rows 0..79 in VGPRs, 80..99 in LDS,
// 100..255 streamed from L2 (624 KB/step instead of 1 MB).
// ---------------------------------------------------------------------------
__global__ __launch_bounds__(1024, 4) void dec_main(
    const int* __restrict__ wids, const float* __restrict__ bo,
    const int* __restrict__ mlab, float* __restrict__ out,
    const float* __restrict__ inpW, const float* __restrict__ embW,
    const float* __restrict__ Uws, const float* __restrict__ WotG, int S) {

  const int tid = threadIdx.x;
  const int b0 = blockIdx.x * 2;

  __shared__ float4 UL[NRL][1024];    // LDS-resident weight rows (80 KB)
  __shared__ float hL[2][256];
  __shared__ float zL[2][1024];
  __shared__ float WotL[NV][260];
  __shared__ float lgp[2][NV][9];
  __shared__ float lg[2][NV];
  __shared__ int stL[4];              // tgt0, tgt1, adj0, adj1
  __shared__ int tsL[2];

  // ---- init ----
  if (tid < 512) hL[tid >> 8][tid & 255] = 0.f;
  if (tid == 0) { stL[0] = 1; stL[1] = 1; stL[2] = 0; stL[3] = 0; tsL[0] = 0; tsL[1] = 0; }
  for (int i = tid; i < NV * 256; i += 1024) WotL[i >> 8][i & 255] = WotG[i];
  __syncthreads();
  if (tid < 128) {
    const int b = tid >> 6, t = tid & 63;
    if (wids[(b0 + b) * NT + t] != 0) atomicAdd(&tsL[b], 1);
  }
  float cst = 0.f;   // c-state for threads tid<512: (b=tid>>8, u=tid&255)

  const float4* Uws4 = (const float4*)Uws;
  const int c = tid;

  // ---- resident weights: VGPR rows ----
  float4 UR[NR4V];
#pragma unroll
  for (int j = 0; j < NR4V; ++j) UR[j] = Uws4[(size_t)j * 1024 + c];
  // ---- resident weights: LDS rows ----
#pragma unroll
  for (int j = 0; j < NRL; ++j) UL[j][c] = Uws4[(size_t)(NR4V + j) * 1024 + c];

  __syncthreads();

  int tsb = 0, ml = 3, hai = 0, hreps = 0;
  if (tid < 2) { tsb = tsL[tid]; ml = mlab[0]; }

#define DOT4(ACC, WV, HV)                                                      \
  ACC = fmaf((WV).x, (HV).x, fmaf((WV).y, (HV).y,                              \
        fmaf((WV).z, (HV).z, fmaf((WV).w, (HV).w, (ACC)))));

  for (int s = 0; s < S; ++s) {
    // table terms for x@W (issued early, hidden under the k-loop)
    const int t0 = stL[0], t1 = stL[1], a0 = stL[2], a1 = stL[3];
    const float e0 = embW[t0 * 1024 + c];
    const float e1 = embW[t1 * 1024 + c];
    const float q0 = inpW[(size_t)((b0) * 64 + a0) * 1024 + c];
    const float q1 = inpW[(size_t)((b0 + 1) * 64 + a1) * 1024 + c];

    // ---- streamed rows [NRES, 64): loads issued first, alternating accs ----
    float s0a = 0.f, s0b = 0.f, s1a = 0.f, s1b = 0.f;
#pragma unroll 13
    for (int k4 = NRES; k4 < 64; ++k4) {
      const float4 wv = Uws4[(size_t)k4 * 1024 + c];
      const float4 h0 = *(const float4*)&hL[0][4 * k4];
      const float4 h1 = *(const float4*)&hL[1][4 * k4];
      if (k4 & 1) { DOT4(s0b, wv, h0) DOT4(s1b, wv, h1) }
      else        { DOT4(s0a, wv, h0) DOT4(s1a, wv, h1) }
    }

    // ---- LDS-resident rows [NR4V, NRES) ----
#pragma unroll
    for (int j = 0; j < NRL; ++j) {
      const int k4 = NR4V + j;
      const float4 wv = UL[j][c];
      const float4 h0 = *(const float4*)&hL[0][4 * k4];
      const float4 h1 = *(const float4*)&hL[1][4 * k4];
      if (j & 1) { DOT4(s0b, wv, h0) DOT4(s1b, wv, h1) }
      else       { DOT4(s0a, wv, h0) DOT4(s1a, wv, h1) }
    }

    // ---- VGPR-resident rows [0, NR4V): pure FMA ----
    float r0a = 0.f, r0b = 0.f, r1a = 0.f, r1b = 0.f;
#pragma unroll
    for (int j = 0; j < NR4V; ++j) {
      const float4 h0 = *(const float4*)&hL[0][4 * j];
      const float4 h1 = *(const float4*)&hL[1][4 * j];
      if (j & 1) { DOT4(r0b, UR[j], h0) DOT4(r1b, UR[j], h1) }
      else       { DOT4(r0a, UR[j], h0) DOT4(r1a, UR[j], h1) }
    }

    zL[0][c] = ((r0a + r0b) + (s0a + s0b)) + e0 + q0;
    zL[1][c] = ((r1a + r1b) + (s1a + s1b)) + e1 + q1;
    __syncthreads();

    // ---- LSTM pointwise (keras gate order i,f,g,o) ----
    if (tid < 512) {
      const int b = tid >> 8, u = tid & 255;
      const float zi = zL[b][u], zf = zL[b][256 + u];
      const float zg = zL[b][512 + u], zo = zL[b][768 + u];
      const float cn = sigf(zf) * cst + sigf(zi) * tanhf(zg);
      cst = cn;
      hL[b][u] = sigf(zo) * tanhf(cn);
    }
    __syncthreads();

    // ---- logits partials: (b, v, kp) each 32 k (k = kp + 8i) ----
    {
      const int b = tid >> 9, idx = tid & 511, v = idx >> 3, kp = idx & 7;
      if (v < NV) {
        float sm = 0.f;
#pragma unroll 8
        for (int i = 0; i < 32; ++i) {
          const int k = kp + 8 * i;
          sm = fmaf(hL[b][k], WotL[v][k], sm);
        }
        lgp[b][v][kp] = sm;
      }
    }
    __syncthreads();
    if (tid < 128) {
      const int b = tid >> 6, v = tid & 63;
      if (v < NV) {
        float sm = bo[v];
#pragma unroll
        for (int k = 0; k < 8; ++k) sm += lgp[b][v][k];
        lg[b][v] = sm;
      }
    }
    __syncthreads();

    // ---- argmax (first-max tie-break) + bookkeeping ----
    if (tid < 2) {
      const int b = tid;
      int am = 0;
      float bv = lg[b][0];
      for (int v = 1; v < NV; ++v) {
        const float x = lg[b][v];
        if (x > bv) { bv = x; am = v; }
      }
      const int preds = (hreps >= ml) ? 2 : am;
      const int res = (hai == tsb) ? 0 : preds;
      out[(size_t)(b0 + b) * S + s] = (float)res;
      const int inc = (preds == 2 && hai < tsb) ? 1 : 0;
      hai += inc;
      hreps = inc ? 0 : hreps;
      stL[b] = preds;
      stL[2 + b] = (hai < tsb) ? hai : hai - 1;
    }
    __syncthreads();
  }
#undef DOT4
}

// ---------------------------------------------------------------------------
extern "C" void kernel_launch(void* const* d_in, const int* in_sizes, int n_in,
                              void* d_out, int out_size, void* d_ws, size_t ws_size,
                              hipStream_t stream) {
  const float* inputs = (const float*)d_in[0];
  const int*   wids   = (const int*)d_in[1];
  const float* embed  = (const float*)d_in[2];
  const float* W      = (const float*)d_in[3];
  const float* Uw     = (const float*)d_in[4];
  const float* bias   = (const float*)d_in[5];
  const float* Wo     = (const float*)d_in[6];
  const float* bo     = (const float*)d_in[7];
  const int*   mlab   = (const int*)d_in[8];
  float* out = (float*)d_out;
  const int S = out_size / NBATCH;   // 192

  char* ws = (char*)d_ws;
  float* inpW = (float*)(ws + WS_INPW);
  float* embW = (float*)(ws + WS_EMBW);
  float* Uws  = (float*)(ws + WS_UWS);
  float* WotG = (float*)(ws + WS_WOT);

  prep_inpw<<<2048, 256, 0, stream>>>(inputs, W, inpW);
  prep_embw<<<48, 256, 0, stream>>>(embed, W, bias, embW);
  prep_uws<<<64, 256, 0, stream>>>(Uw, Uws);
  prep_wot<<<1, 256, 0, stream>>>(Wo, WotG);
  dec_main<<<64, 1024, 0, stream>>>(wids, bo, mlab, out, inpW, embW, Uws, WotG, S);
}

// Round 6
// 2194.772 us; speedup vs baseline: 1.1653x; 1.1653x over previous
//
#include <hip/hip_runtime.h>
#include <cmath>

typedef unsigned int u32;
typedef unsigned long long u64;

// Problem constants
#define NBATCH 128
#define NT 64
#define ND 768
#define NU 256
#define NV 48
#define NGRP 32    // batch groups (4 batches each)
#define NSL 8      // column slices per group (128 cols each)

// ws layout (bytes)
#define WS_INPW 0                          // inpW[128*64][1024] f32 = 33,554,432
#define WS_EMBW 33554432                   // embW[48][1024] f32   = 196,608
#define WS_UWS  (WS_EMBW + 196608)         // Uws [64][1024] float4 = 1,048,576
#define WS_WOT  (WS_UWS + 1048576)         // WotG[48][256] f32    = 49,152
#define WS_HG   (WS_WOT + 49152)           // hG[2][32][4][256] f32 = 262,144
#define WS_CNT  (WS_HG + 262144)           // cnt[32*S] u32

__device__ __forceinline__ float sigf(float x) { return 1.0f / (1.0f + expf(-x)); }

union F2U { u64 q; float2 f; };

// ---------------------------------------------------------------------------
// inpW[(b*64+t)][c] = inputs[b][t][:] @ W[256:1024][c]   (M=8192,N=1024,K=768)
// ---------------------------------------------------------------------------
__global__ __launch_bounds__(256) void prep_inpw(
    const float* __restrict__ inputs, const float* __restrict__ W,
    float* __restrict__ inpW) {
  __shared__ float Af[64][36];
  __shared__ float Bf[32][68];
  const int mt = blockIdx.x >> 4, nt = blockIdx.x & 15;
  const int m0 = mt * 64, n0 = nt * 64;
  const int tid = threadIdx.x;
  const int ty = tid >> 4, tx = tid & 15;
  const float4* in4 = (const float4*)inputs;
  const float4* W4 = (const float4*)W;
  float acc[4][4] = {};
  for (int kt = 0; kt < 24; ++kt) {
    __syncthreads();
    {
      int idx = tid;
#pragma unroll
      for (int r = 0; r < 2; ++r, idx += 256) {
        const int row = idx >> 3, k4 = idx & 7;
        const float4 a = in4[(size_t)(m0 + row) * 192 + kt * 8 + k4];
        *(float4*)&Af[row][4 * k4] = a;
      }
    }
    {
      int idx = tid;
#pragma unroll
      for (int r = 0; r < 2; ++r, idx += 256) {
        const int kk = idx >> 4, c4 = idx & 15;
        const float4 bv = W4[(size_t)(256 + kt * 32 + kk) * 256 + (n0 >> 2) + c4];
        *(float4*)&Bf[kk][4 * c4] = bv;
      }
    }
    __syncthreads();
#pragma unroll 4
    for (int kk = 0; kk < 32; ++kk) {
      float av[4], bv[4];
#pragma unroll
      for (int q = 0; q < 4; ++q) av[q] = Af[ty * 4 + q][kk];
#pragma unroll
      for (int q = 0; q < 4; ++q) bv[q] = Bf[kk][tx * 4 + q];
#pragma unroll
      for (int i = 0; i < 4; ++i)
#pragma unroll
        for (int q = 0; q < 4; ++q) acc[i][q] = fmaf(av[i], bv[q], acc[i][q]);
    }
  }
#pragma unroll
  for (int i = 0; i < 4; ++i) {
    const float4 o = make_float4(acc[i][0], acc[i][1], acc[i][2], acc[i][3]);
    ((float4*)inpW)[(((size_t)(m0 + ty * 4 + i)) * 1024 + n0 + tx * 4) >> 2] = o;
  }
}

// ---------------------------------------------------------------------------
// embW[v][c] = bias[c] + embed[v][:] @ W[0:256][c]
// ---------------------------------------------------------------------------
__global__ __launch_bounds__(256) void prep_embw(
    const float* __restrict__ embed, const float* __restrict__ W,
    const float* __restrict__ bias, float* __restrict__ embW) {
  const int v = blockIdx.x, tid = threadIdx.x;
  const float4* W4 = (const float4*)W;
  float4 acc = ((const float4*)bias)[tid];
  for (int e = 0; e < 256; ++e) {
    const float s = embed[v * 256 + e];
    const float4 w = W4[(size_t)e * 256 + tid];
    acc.x = fmaf(s, w.x, acc.x); acc.y = fmaf(s, w.y, acc.y);
    acc.z = fmaf(s, w.z, acc.z); acc.w = fmaf(s, w.w, acc.w);
  }
  ((float4*)embW)[v * 256 + tid] = acc;
}

// ---------------------------------------------------------------------------
// Uws element (k4, c) = float4{ Uw[4k4+0][c], .., Uw[4k4+3][c] }
// ---------------------------------------------------------------------------
__global__ __launch_bounds__(256) void prep_uws(
    const float* __restrict__ Uw, float* __restrict__ Uws) {
  const int k4 = blockIdx.x, tid = threadIdx.x;
#pragma unroll
  for (int q = 0; q < 4; ++q) {
    const int cc = tid + 256 * q;
    float4 o;
    o.x = Uw[(size_t)(4 * k4 + 0) * 1024 + cc];
    o.y = Uw[(size_t)(4 * k4 + 1) * 1024 + cc];
    o.z = Uw[(size_t)(4 * k4 + 2) * 1024 + cc];
    o.w = Uw[(size_t)(4 * k4 + 3) * 1024 + cc];
    ((float4*)Uws)[(size_t)k4 * 1024 + cc] = o;
  }
}

// Wot[v][u] = Wo[u][v]; zero sync counters
__global__ void prep_misc(const float* __restrict__ Wo, float* __restrict__ WotG,
                          u32* __restrict__ cnt, int S) {
  const int tid = threadIdx.x;
  for (int i = tid; i < NGRP * S; i += 256) cnt[i] = 0u;
  for (int i = tid; i < NV * NU; i += 256) {
    int v = i >> 8, u = i & 255;
    WotG[i] = Wo[u * NV + v];
  }
}

// ---------------------------------------------------------------------------
// Persistent decoder: 256 blocks x 512 threads, 1 block/CU (LDS-forced).
// Block = (group g = blockIdx&31 : 4 batches, slice j = blockIdx>>5 : units
// [32j,32j+32) i.e. 128 gate-cols). Uw slice (128 KB) lives in LDS, loaded
// once: ZERO per-step weight streaming. Per step: z-slice (4c x 4b x 16-way
// k-split, shuffle reduce) + x-table terms -> pointwise LSTM (c in regs) ->
// h-slice to hG via IC -> single 8-wide flag sync -> 1 float2/thread gather
// -> redundant logits/argmax/bookkeeping per block (deterministic).
// ---------------------------------------------------------------------------
__global__ __launch_bounds__(512, 2) void dec_main(
    const int* __restrict__ wids, const float* __restrict__ bo,
    const int* __restrict__ mlab, float* __restrict__ out,
    const float* __restrict__ inpW, const float* __restrict__ embW,
    const float* __restrict__ Uws, const float* __restrict__ WotG,
    float* __restrict__ hG, u32* __restrict__ cnt, int S) {

  const int tid = threadIdx.x;
  const int g = blockIdx.x & 31;     // batch group
  const int j = blockIdx.x >> 5;     // column slice
  const int b0 = g * 4;
  const int cg = tid >> 4, kg = tid & 15;   // col-group of 4, k-group of 4 k4s

  __shared__ float4 WlL[512][17];    // private weight rows, stride 17: no conflicts
  __shared__ float4 hL4[256];        // h[b][64] as float4
  __shared__ float zL[128][4];       // h@Uw partial z (local cols x batches)
  __shared__ float xT[4][132];       // x-table term per (b, local col)
  __shared__ float lg[4][48];        // logits
  __shared__ int stL[8];             // tgt[4], adj[4]

  const float4* Uws4 = (const float4*)Uws;
  const float4* Wot4 = (const float4*)WotG;
  u32* hG32 = (u32*)hG;
  const u64* hG64 = (const u64*)hG;

  // ---- init ----
  if (tid < 256) hL4[tid] = make_float4(0.f, 0.f, 0.f, 0.f);
  if (tid == 0) {
    stL[0] = stL[1] = stL[2] = stL[3] = 1;   // BOS
    stL[4] = stL[5] = stL[6] = stL[7] = 0;   // adj = 0
  }
  int tsb = 0, ml = 3, hai = 0, hreps = 0;
  if (tid < 4) {
    int c = 0;
    for (int i = 0; i < NT; ++i) c += (wids[(b0 + tid) * NT + i] != 0) ? 1 : 0;
    tsb = c;
    ml = mlab[0];
  }
  // ---- load weight slice into LDS (once) ----
#pragma unroll
  for (int i = 0; i < 4; ++i)
#pragma unroll
    for (int c = 0; c < 4; ++c) {
      const int lc = 4 * cg + c;
      const int gc = ((lc >> 5) << 8) + (j << 5) + (lc & 31);
      WlL[tid][i * 4 + c] = Uws4[(size_t)(kg + 16 * i) * 1024 + gc];
    }
  __syncthreads();

  float cst = 0.f;   // c-state: threads tid<128 own (b=tid>>5, u=tid&31)

  const int bx = tid >> 7, lcx = tid & 127;
  const int gcx = ((lcx >> 5) << 8) + (j << 5) + (lcx & 31);

  for (int s = 0; s < S; ++s) {
    const int par = (s + 1) & 1;

    // ---- x-table term (uses tgt/adj decided at end of prev step) ----
    const float xv = embW[stL[bx] * 1024 + gcx]
                   + inpW[((size_t)(b0 + bx) * 64 + stL[4 + bx]) * 1024 + gcx];

    // ---- h @ Uw slice: 4 cols x 4 batches x 4 k4 per thread ----
    float acc[4][4] = {};
#pragma unroll
    for (int i = 0; i < 4; ++i) {
      const int k4 = kg + 16 * i;
      float4 hb[4];
#pragma unroll
      for (int b = 0; b < 4; ++b) hb[b] = hL4[b * 64 + k4];
#pragma unroll
      for (int c = 0; c < 4; ++c) {
        const float4 w = WlL[tid][i * 4 + c];
#pragma unroll
        for (int b = 0; b < 4; ++b)
          acc[c][b] = fmaf(w.x, hb[b].x, fmaf(w.y, hb[b].y,
                      fmaf(w.z, hb[b].z, fmaf(w.w, hb[b].w, acc[c][b]))));
      }
    }
    // k-reduce across the 16 kg lanes (lane-consecutive groups)
#pragma unroll
    for (int m = 1; m <= 8; m <<= 1)
#pragma unroll
      for (int c = 0; c < 4; ++c)
#pragma unroll
        for (int b = 0; b < 4; ++b)
          acc[c][b] += __shfl_xor(acc[c][b], m);
    if (kg == 0) {
#pragma unroll
      for (int c = 0; c < 4; ++c)
#pragma unroll
        for (int b = 0; b < 4; ++b) zL[4 * cg + c][b] = acc[c][b];
    }
    xT[bx][lcx] = xv;
    __syncthreads();  // B1: zL + xT ready

    // ---- pointwise LSTM for own 32 units x 4 batches ----
    if (tid < 128) {
      const int b = tid >> 5, u = tid & 31;
      const float zi = zL[u][b] + xT[b][u];
      const float zf = zL[32 + u][b] + xT[b][32 + u];
      const float zg = zL[64 + u][b] + xT[b][64 + u];
      const float zo = zL[96 + u][b] + xT[b][96 + u];
      const float cn = sigf(zf) * cst + sigf(zi) * tanhf(zg);
      cst = cn;
      const float hv = sigf(zo) * tanhf(cn);
      __hip_atomic_store(&hG32[(((size_t)par * NGRP + g) * 4 + b) * 256 + (j * 32 + u)],
                         __float_as_uint(hv), __ATOMIC_RELAXED, __HIP_MEMORY_SCOPE_AGENT);
    }
    asm volatile("s_waitcnt vmcnt(0)" ::: "memory");
    __syncthreads();  // B2: h stores drained

    if (tid == 0) {
      atomicAdd(&cnt[g * S + s], 1u);
      while (__hip_atomic_load(&cnt[g * S + s], __ATOMIC_RELAXED,
                               __HIP_MEMORY_SCOPE_AGENT) < (u32)NSL)
        __builtin_amdgcn_s_sleep(1);
    }
    __syncthreads();  // B3: all 8 slices published

    // ---- gather full h(s+1): one float2 per thread ----
    {
      const int b = tid >> 7, up = tid & 127;
      F2U u2;
      u2.q = __hip_atomic_load(&hG64[(((size_t)par * NGRP + g) * 4 + b) * 128 + up],
                               __ATOMIC_RELAXED, __HIP_MEMORY_SCOPE_AGENT);
      ((float2*)hL4)[b * 128 + up] = u2.f;
    }
    __syncthreads();  // B4: hL = h(s+1)

    // ---- logits (redundant per block): (b, v, k-half) ----
    if (tid < 384) {
      const int b = tid / 96, r = tid - 96 * b, v = r >> 1, kq = r & 1;
      float s0 = 0.f, s1 = 0.f;
#pragma unroll 8
      for (int i = 0; i < 32; i += 2) {
        const float4 h4a = hL4[b * 64 + kq * 32 + i];
        const float4 w4a = Wot4[v * 64 + kq * 32 + i];
        const float4 h4b = hL4[b * 64 + kq * 32 + i + 1];
        const float4 w4b = Wot4[v * 64 + kq * 32 + i + 1];
        s0 = fmaf(h4a.x, w4a.x, fmaf(h4a.y, w4a.y, fmaf(h4a.z, w4a.z, fmaf(h4a.w, w4a.w, s0))));
        s1 = fmaf(h4b.x, w4b.x, fmaf(h4b.y, w4b.y, fmaf(h4b.z, w4b.z, fmaf(h4b.w, w4b.w, s1))));
      }
      float sum = s0 + s1;
      sum += __shfl_xor(sum, 1);
      if (kq == 0) lg[b][v] = sum + bo[v];
    }
    __syncthreads();  // B5: logits ready

    // ---- argmax + bookkeeping (redundant per block; deterministic) ----
    if (tid < 4) {
      const int b = tid;
      int am = 0;
      float bv = lg[b][0];
      for (int v = 1; v < NV; ++v) {
        const float x = lg[b][v];
        if (x > bv) { bv = x; am = v; }
      }
      const int preds = (hreps >= ml) ? 2 : am;
      const int res = (hai == tsb) ? 0 : preds;
      if (j == 0) out[(size_t)(b0 + b) * S + s] = (float)res;
      const int inc = (preds == 2 && hai < tsb) ? 1 : 0;
      hai += inc;
      hreps = inc ? 0 : hreps;
      stL[b] = preds;
      stL[4 + b] = (hai < tsb) ? hai : hai - 1;
    }
    __syncthreads();  // B6: stL ready for next step
  }
}

// ---------------------------------------------------------------------------
extern "C" void kernel_launch(void* const* d_in, const int* in_sizes, int n_in,
                              void* d_out, int out_size, void* d_ws, size_t ws_size,
                              hipStream_t stream) {
  const float* inputs = (const float*)d_in[0];
  const int*   wids   = (const int*)d_in[1];
  const float* embed  = (const float*)d_in[2];
  const float* W      = (const float*)d_in[3];
  const float* Uw     = (const float*)d_in[4];
  const float* bias   = (const float*)d_in[5];
  const float* Wo     = (const float*)d_in[6];
  const float* bo     = (const float*)d_in[7];
  const int*   mlab   = (const int*)d_in[8];
  float* out = (float*)d_out;
  const int S = out_size / NBATCH;   // 192

  char* ws = (char*)d_ws;
  float* inpW = (float*)(ws + WS_INPW);
  float* embW = (float*)(ws + WS_EMBW);
  float* Uws  = (float*)(ws + WS_UWS);
  float* WotG = (float*)(ws + WS_WOT);
  float* hG   = (float*)(ws + WS_HG);
  u32*   cnt  = (u32*)(ws + WS_CNT);

  prep_inpw<<<2048, 256, 0, stream>>>(inputs, W, inpW);
  prep_embw<<<48, 256, 0, stream>>>(embed, W, bias, embW);
  prep_uws<<<64, 256, 0, stream>>>(Uw, Uws);
  prep_misc<<<1, 256, 0, stream>>>(Wo, WotG, cnt, S);
  dec_main<<<256, 512, 0, stream>>>(wids, bo, mlab, out, inpW, embW, Uws, WotG,
                                    hG, cnt, S);
}

// Round 8
// 1360.635 us; speedup vs baseline: 1.8797x; 1.6130x over previous
//
#include <hip/hip_runtime.h>
#include <cmath>

typedef unsigned int u32;
typedef unsigned long long u64;

// Problem constants
#define NBATCH 128
#define NT 64
#define ND 768
#define NU 256
#define NV 48
#define NGRP 32    // batch groups (4 batches each)
#define NSL 8      // unit slices per group (32 units = 128 gate-cols each)

// ws layout (bytes)
#define WS_INPW 0                          // inpW[128*64][1024] f32 = 33,554,432
#define WS_EMBW 33554432                   // embW[48][1024] f32   = 196,608
#define WS_UWS  (WS_EMBW + 196608)         // Uws [64][1024] float4 = 1,048,576
#define WS_HG   (WS_UWS + 1048576)         // hG[2][32][4][256] f32 = 262,144
#define WS_PG   (WS_HG + 262144)           // pgG[2][32][4*48*8] f32 = 393,216
#define WS_FLAG (WS_PG + 393216)           // flagG[32][8] u32 = 1,024

__device__ __forceinline__ float sigf(float x) { return 1.0f / (1.0f + expf(-x)); }

union F2U { u64 q; float2 f; };

// ---------------------------------------------------------------------------
// inpW[(b*64+t)][c] = inputs[b][t][:] @ W[256:1024][c]   (M=8192,N=1024,K=768)
// ---------------------------------------------------------------------------
__global__ __launch_bounds__(256) void prep_inpw(
    const float* __restrict__ inputs, const float* __restrict__ W,
    float* __restrict__ inpW) {
  __shared__ float Af[64][36];
  __shared__ float Bf[32][68];
  const int mt = blockIdx.x >> 4, nt = blockIdx.x & 15;
  const int m0 = mt * 64, n0 = nt * 64;
  const int tid = threadIdx.x;
  const int ty = tid >> 4, tx = tid & 15;
  const float4* in4 = (const float4*)inputs;
  const float4* W4 = (const float4*)W;
  float acc[4][4] = {};
  for (int kt = 0; kt < 24; ++kt) {
    __syncthreads();
    {
      int idx = tid;
#pragma unroll
      for (int r = 0; r < 2; ++r, idx += 256) {
        const int row = idx >> 3, k4 = idx & 7;
        const float4 a = in4[(size_t)(m0 + row) * 192 + kt * 8 + k4];
        *(float4*)&Af[row][4 * k4] = a;
      }
    }
    {
      int idx = tid;
#pragma unroll
      for (int r = 0; r < 2; ++r, idx += 256) {
        const int kk = idx >> 4, c4 = idx & 15;
        const float4 bv = W4[(size_t)(256 + kt * 32 + kk) * 256 + (n0 >> 2) + c4];
        *(float4*)&Bf[kk][4 * c4] = bv;
      }
    }
    __syncthreads();
#pragma unroll 4
    for (int kk = 0; kk < 32; ++kk) {
      float av[4], bv[4];
#pragma unroll
      for (int q = 0; q < 4; ++q) av[q] = Af[ty * 4 + q][kk];
#pragma unroll
      for (int q = 0; q < 4; ++q) bv[q] = Bf[kk][tx * 4 + q];
#pragma unroll
      for (int i = 0; i < 4; ++i)
#pragma unroll
        for (int q = 0; q < 4; ++q) acc[i][q] = fmaf(av[i], bv[q], acc[i][q]);
    }
  }
#pragma unroll
  for (int i = 0; i < 4; ++i) {
    const float4 o = make_float4(acc[i][0], acc[i][1], acc[i][2], acc[i][3]);
    ((float4*)inpW)[(((size_t)(m0 + ty * 4 + i)) * 1024 + n0 + tx * 4) >> 2] = o;
  }
}

// ---------------------------------------------------------------------------
// embW[v][c] = bias[c] + embed[v][:] @ W[0:256][c]
// ---------------------------------------------------------------------------
__global__ __launch_bounds__(256) void prep_embw(
    const float* __restrict__ embed, const float* __restrict__ W,
    const float* __restrict__ bias, float* __restrict__ embW) {
  const int v = blockIdx.x, tid = threadIdx.x;
  const float4* W4 = (const float4*)W;
  float4 acc = ((const float4*)bias)[tid];
  for (int e = 0; e < 256; ++e) {
    const float s = embed[v * 256 + e];
    const float4 w = W4[(size_t)e * 256 + tid];
    acc.x = fmaf(s, w.x, acc.x); acc.y = fmaf(s, w.y, acc.y);
    acc.z = fmaf(s, w.z, acc.z); acc.w = fmaf(s, w.w, acc.w);
  }
  ((float4*)embW)[v * 256 + tid] = acc;
}

// ---------------------------------------------------------------------------
// Uws element (k4, c) = float4{ Uw[4k4+0][c], .., Uw[4k4+3][c] }
// ---------------------------------------------------------------------------
__global__ __launch_bounds__(256) void prep_uws(
    const float* __restrict__ Uw, float* __restrict__ Uws) {
  const int k4 = blockIdx.x, tid = threadIdx.x;
#pragma unroll
  for (int q = 0; q < 4; ++q) {
    const int cc = tid + 256 * q;
    float4 o;
    o.x = Uw[(size_t)(4 * k4 + 0) * 1024 + cc];
    o.y = Uw[(size_t)(4 * k4 + 1) * 1024 + cc];
    o.z = Uw[(size_t)(4 * k4 + 2) * 1024 + cc];
    o.w = Uw[(size_t)(4 * k4 + 3) * 1024 + cc];
    ((float4*)Uws)[(size_t)k4 * 1024 + cc] = o;
  }
}

// ---------------------------------------------------------------------------
// Persistent decoder: 256 blocks x 512 threads, 1 block/CU (LDS-forced).
// Block (g = blockIdx&31, j = blockIdx>>5): 4 batches, units [32j, 32j+32).
// Uw slice in LDS (128 KB, loaded once). Per step: z (4-way k-split, h-read
// broadcast) -> B1 -> pointwise (c in regs) + h-store -> B2 -> LOCAL partial
// logits + store -> vmcnt -> B2b -> per-slice flag (s+1) -> 8-thread poll ->
// B3 -> gather h + sum partials (fixed j order) + wave-parallel shfl argmax
// + bookkeeping -> B4. Parity double-buffered hG/pgG; monotonic flags make
// arbitrary skew safe. ALL cross-block data (h, pg, flags) moves through
// agent-scope atomics (IC-coherent) — R7's plain pg store raced via the
// non-coherent per-XCD L2 (passed first launch, diverged on replays).
// ---------------------------------------------------------------------------
__global__ __launch_bounds__(512, 2) void dec_main(
    const int* __restrict__ wids, const float* __restrict__ bo,
    const int* __restrict__ mlab, float* __restrict__ out,
    const float* __restrict__ inpW, const float* __restrict__ embW,
    const float* __restrict__ Uws, const float* __restrict__ Wo,
    float* __restrict__ hG, float* __restrict__ pgG,
    u32* __restrict__ flagG, int S) {

  const int tid = threadIdx.x;
  const int g = blockIdx.x & 31;     // batch group
  const int j = blockIdx.x >> 5;     // unit slice
  const int b0 = g * 4;

  __shared__ float4 WlS[64][128];    // Uw slice, [k4][local col]   (128 KB)
  __shared__ float4 hL4[256];        // h[b][64] float4              (4 KB)
  __shared__ float hOwn[4][32];      // own-unit h (for partials)
  __shared__ float zLp[4][128];      // reduced h@Uw partials
  __shared__ float xTp[4][128];      // x-table term
  __shared__ float WoS[32][48];      // Wo rows of own units         (6 KB)
  __shared__ float boS[48];
  __shared__ int tsL[4], haiL[4], hrepL[4], stL[8];
  __shared__ int mlL;

  const float4* Uws4 = (const float4*)Uws;
  u32* hG32 = (u32*)hG;
  const u64* hG64 = (const u64*)hG;
  u32* pg32 = (u32*)pgG;
  const u64* pg64 = (const u64*)pgG;

  // ---- init ----
  if (tid < 256) hL4[tid] = make_float4(0.f, 0.f, 0.f, 0.f);
  for (int idx = tid; idx < 8192; idx += 512) {
    const int k4 = idx >> 7, lc = idx & 127;
    const int gc = ((lc >> 5) << 8) + (j << 5) + (lc & 31);
    WlS[k4][lc] = Uws4[(size_t)k4 * 1024 + gc];
  }
  for (int idx = tid; idx < 32 * 48; idx += 512) {
    const int u = idx / 48, v = idx - 48 * u;
    WoS[u][v] = Wo[(j * 32 + u) * 48 + v];
  }
  if (tid < 48) boS[tid] = bo[tid];
  if (tid < 4) {
    int c = 0;
    for (int t = 0; t < NT; ++t) c += (wids[(b0 + tid) * NT + t] != 0) ? 1 : 0;
    tsL[tid] = c; haiL[tid] = 0; hrepL[tid] = 0;
    stL[tid] = 1; stL[4 + tid] = 0;
  }
  if (tid == 0) mlL = mlab[0];
  __syncthreads();

  float cst = 0.f;   // c-state: threads tid<128 own (b=tid>>5, u=tid&31)

  const int lc = tid >> 2, kg = tid & 3;    // z mapping: col, k-split
  const int bb = tid >> 7, lcc = tid & 127; // xv mapping
  const int gcx = ((lcc >> 5) << 8) + (j << 5) + (lcc & 31);
  const int wv = tid >> 6, ln = tid & 63;   // wave, lane

  for (int s = 0; s < S; ++s) {
    const int par = s & 1;

    // ---- x-table term (global loads overlap the z k-loop) ----
    const float xv = embW[stL[bb] * 1024 + gcx]
                   + inpW[((size_t)(b0 + bb) * 64 + stL[4 + bb]) * 1024 + gcx];

    // ---- z = h @ Uw slice: 1 col x 4 batches x 16 k4 per thread ----
    float a0 = 0.f, a1 = 0.f, a2 = 0.f, a3 = 0.f;
#pragma unroll
    for (int i = 0; i < 16; ++i) {
      const int k4 = kg + 4 * i;
      const float4 w = WlS[k4][lc];
      const float4 h0 = hL4[k4], h1 = hL4[64 + k4];
      const float4 h2 = hL4[128 + k4], h3 = hL4[192 + k4];
      a0 = fmaf(w.x, h0.x, fmaf(w.y, h0.y, fmaf(w.z, h0.z, fmaf(w.w, h0.w, a0))));
      a1 = fmaf(w.x, h1.x, fmaf(w.y, h1.y, fmaf(w.z, h1.z, fmaf(w.w, h1.w, a1))));
      a2 = fmaf(w.x, h2.x, fmaf(w.y, h2.y, fmaf(w.z, h2.z, fmaf(w.w, h2.w, a2))));
      a3 = fmaf(w.x, h3.x, fmaf(w.y, h3.y, fmaf(w.z, h3.z, fmaf(w.w, h3.w, a3))));
    }
#pragma unroll
    for (int m = 1; m <= 2; m <<= 1) {
      a0 += __shfl_xor(a0, m); a1 += __shfl_xor(a1, m);
      a2 += __shfl_xor(a2, m); a3 += __shfl_xor(a3, m);
    }
    if (kg == 0) { zLp[0][lc] = a0; zLp[1][lc] = a1; zLp[2][lc] = a2; zLp[3][lc] = a3; }
    xTp[bb][lcc] = xv;
    __syncthreads();  // B1

    // ---- pointwise LSTM (keras gate order i,f,g,o) + publish h-slice ----
    if (tid < 128) {
      const int b = tid >> 5, u = tid & 31;
      const float zi = zLp[b][u] + xTp[b][u];
      const float zf = zLp[b][32 + u] + xTp[b][32 + u];
      const float zg = zLp[b][64 + u] + xTp[b][64 + u];
      const float zo = zLp[b][96 + u] + xTp[b][96 + u];
      const float cn = sigf(zf) * cst + sigf(zi) * tanhf(zg);
      cst = cn;
      const float hv = sigf(zo) * tanhf(cn);
      hOwn[b][u] = hv;
      __hip_atomic_store(&hG32[(((size_t)par * NGRP + g) * 4 + b) * 256 + (j * 32 + u)],
                         __float_as_uint(hv), __ATOMIC_RELAXED, __HIP_MEMORY_SCOPE_AGENT);
    }
    __syncthreads();  // B2: hOwn visible

    // ---- local partial logits (own 32 units, 4 batches x 48 vocab) ----
    // IC-coherent atomic store: plain store raced via per-XCD L2 (R7 bug).
    if (tid < 256) {
      const int b = tid >> 6, v = tid & 63;
      if (v < NV) {
        float sm = 0.f;
#pragma unroll 8
        for (int u = 0; u < 32; ++u) sm = fmaf(hOwn[b][u], WoS[u][v], sm);
        __hip_atomic_store(
            &pg32[((size_t)par * NGRP + g) * 1536 + (b * NV + v) * 8 + j],
            __float_as_uint(sm), __ATOMIC_RELAXED, __HIP_MEMORY_SCOPE_AGENT);
      }
    }
    asm volatile("s_waitcnt vmcnt(0)" ::: "memory");
    __syncthreads();  // B2b: every wave's h/pg stores drained to IC

    if (tid == 0)
      __hip_atomic_store(&flagG[g * 8 + j], (u32)(s + 1),
                         __ATOMIC_RELAXED, __HIP_MEMORY_SCOPE_AGENT);
    if (tid < 8) {
      while (__hip_atomic_load(&flagG[g * 8 + tid], __ATOMIC_RELAXED,
                               __HIP_MEMORY_SCOPE_AGENT) < (u32)(s + 1))
        __builtin_amdgcn_s_sleep(1);
    }
    __syncthreads();  // B3: all 8 slices published step s+1

    // ---- gather full h(s+1) ----
    {
      const int b = tid >> 7, up = tid & 127;
      F2U u2;
      u2.q = __hip_atomic_load(&hG64[(((size_t)par * NGRP + g) * 4 + b) * 128 + up],
                               __ATOMIC_RELAXED, __HIP_MEMORY_SCOPE_AGENT);
      ((float2*)hL4)[b * 128 + up] = u2.f;
    }

    // ---- logits sum (fixed j order) + wave-parallel first-max argmax ----
    if (wv < 4) {
      float bv = -3.0e38f;
      int am = ln;
      if (ln < NV) {
        const size_t pb = ((size_t)par * NGRP + g) * 768 + (size_t)(wv * NV + ln) * 4;
        F2U q0, q1, q2, q3;
        q0.q = __hip_atomic_load(&pg64[pb + 0], __ATOMIC_RELAXED, __HIP_MEMORY_SCOPE_AGENT);
        q1.q = __hip_atomic_load(&pg64[pb + 1], __ATOMIC_RELAXED, __HIP_MEMORY_SCOPE_AGENT);
        q2.q = __hip_atomic_load(&pg64[pb + 2], __ATOMIC_RELAXED, __HIP_MEMORY_SCOPE_AGENT);
        q3.q = __hip_atomic_load(&pg64[pb + 3], __ATOMIC_RELAXED, __HIP_MEMORY_SCOPE_AGENT);
        float sm = q0.f.x + q0.f.y;
        sm += q1.f.x; sm += q1.f.y;
        sm += q2.f.x; sm += q2.f.y;
        sm += q3.f.x; sm += q3.f.y;
        bv = sm + boS[ln];
      }
#pragma unroll
      for (int m = 32; m >= 1; m >>= 1) {
        const float ov = __shfl_xor(bv, m);
        const int oi = __shfl_xor(am, m);
        if (ov > bv || (ov == bv && oi < am)) { bv = ov; am = oi; }
      }
      if (ln == 0) {
        const int b = wv;
        const int tsb = tsL[b], hai = haiL[b], hreps = hrepL[b];
        const int preds = (hreps >= mlL) ? 2 : am;
        const int res = (hai == tsb) ? 0 : preds;
        if (j == 0) out[(size_t)(b0 + b) * S + s] = (float)res;
        const int inc = (preds == 2 && hai < tsb) ? 1 : 0;
        const int hai2 = hai + inc;
        haiL[b] = hai2;
        hrepL[b] = inc ? 0 : hreps;
        stL[b] = preds;
        stL[4 + b] = (hai2 < tsb) ? hai2 : hai2 - 1;
      }
    }
    __syncthreads();  // B4: hL4 + stL ready for next step
  }
}

// ---------------------------------------------------------------------------
extern "C" void kernel_launch(void* const* d_in, const int* in_sizes, int n_in,
                              void* d_out, int out_size, void* d_ws, size_t ws_size,
                              hipStream_t stream) {
  const float* inputs = (const float*)d_in[0];
  const int*   wids   = (const int*)d_in[1];
  const float* embed  = (const float*)d_in[2];
  const float* W      = (const float*)d_in[3];
  const float* Uw     = (const float*)d_in[4];
  const float* bias   = (const float*)d_in[5];
  const float* Wo     = (const float*)d_in[6];
  const float* bo     = (const float*)d_in[7];
  const int*   mlab   = (const int*)d_in[8];
  float* out = (float*)d_out;
  const int S = out_size / NBATCH;   // 192

  char* ws = (char*)d_ws;
  float* inpW  = (float*)(ws + WS_INPW);
  float* embW  = (float*)(ws + WS_EMBW);
  float* Uws   = (float*)(ws + WS_UWS);
  float* hG    = (float*)(ws + WS_HG);
  float* pgG   = (float*)(ws + WS_PG);
  u32*   flagG = (u32*)(ws + WS_FLAG);

  hipMemsetAsync(flagG, 0, NGRP * NSL * sizeof(u32), stream);
  prep_inpw<<<2048, 256, 0, stream>>>(inputs, W, inpW);
  prep_embw<<<48, 256, 0, stream>>>(embed, W, bias, embW);
  prep_uws<<<64, 256, 0, stream>>>(Uw, Uws);
  dec_main<<<256, 512, 0, stream>>>(wids, bo, mlab, out, inpW, embW, Uws, Wo,
                                    hG, pgG, flagG, S);
}